// Round 1
// baseline (7139.887 us; speedup 1.0000x reference)
//
#include <hip/hip_runtime.h>
#include <hip/hip_bf16.h>
#include <math.h>

#define MOTIF  283
#define HIDDEN 256
#define DEPTH  7
#define KPROF  20
#define CHUNK  512
#define NCHUNK 256   // batch(2) * max_n_peaks(128)
#define NTOK   (NCHUNK * CHUNK)   // 131072

using bf16 = __hip_bfloat16;

__device__ __forceinline__ float b2f(bf16 v){ return __bfloat162float(v); }
__device__ __forceinline__ bf16  f2b(float v){ return __float2bfloat16(v); }

// ---------------------------------------------------------------- transposes
// wt[m][c] = w_proj[c][m]   (283 x 256)
__global__ __launch_bounds__(256) void k_transpose_wproj(
    const float* __restrict__ w, float* __restrict__ wt){
  int idx = blockIdx.x * 256 + threadIdx.x;
  if (idx < MOTIF * HIDDEN){
    int m = idx / HIDDEN, c = idx % HIDDEN;
    wt[idx] = w[c * MOTIF + m];
  }
}

// wtow[i][(ci*3+k)*256 + co] = tower_w[i][co][ci][k]
__global__ __launch_bounds__(256) void k_transpose_tower(
    const float* __restrict__ w, float* __restrict__ wt){
  int idx = blockIdx.x * 256 + threadIdx.x;
  const int PER = HIDDEN * HIDDEN * 3;   // 196608
  if (idx < DEPTH * PER){
    int i  = idx / PER;
    int r  = idx % PER;
    int co = r & 255;
    int ck = r >> 8;          // ci*3 + k
    int ci = ck / 3, k = ck % 3;
    wt[idx] = w[(((size_t)i * HIDDEN + co) * HIDDEN + ci) * 3 + k];
  }
}

// ---------------------------------------------------------------- projection
// h0[n][c][l] = sum_m x[token][m] * w_proj[c][m],  token = n*512 + l
// block: 32 tokens x 128 channels; thread: 4 tokens x 4 channels
__global__ __launch_bounds__(256) void k_proj(
    const float* __restrict__ x, const float* __restrict__ wt,
    bf16* __restrict__ hout){
  __shared__ float xs[32 * MOTIF];   // 36224 B
  const int t0  = blockIdx.x * 32;
  const int c0  = blockIdx.y * 128;
  const int tid = threadIdx.x;
  for (int i = tid; i < 32 * MOTIF; i += 256)
    xs[i] = x[(size_t)t0 * MOTIF + i];
  __syncthreads();

  const int tg = tid & 7;        // token group -> 4 tokens
  const int cg = tid >> 3;       // 0..31      -> 4 channels
  const int tb = tg * 4;
  const int c  = c0 + cg * 4;

  float acc[4][4] = {};
  for (int m = 0; m < MOTIF; ++m){
    const float4 wv = *(const float4*)(wt + m * HIDDEN + c);
    #pragma unroll
    for (int tt = 0; tt < 4; ++tt){
      const float xv = xs[(tb + tt) * MOTIF + m];
      acc[tt][0] += xv * wv.x;
      acc[tt][1] += xv * wv.y;
      acc[tt][2] += xv * wv.z;
      acc[tt][3] += xv * wv.w;
    }
  }
  #pragma unroll
  for (int tt = 0; tt < 4; ++tt){
    const int token = t0 + tb + tt;
    const int n = token >> 9, l = token & 511;
    #pragma unroll
    for (int cc = 0; cc < 4; ++cc)
      hout[((size_t)(n * HIDDEN + c + cc) << 9) + l] = f2b(acc[tt][cc]);
  }
}

// ---------------------------------------------------------------- conv tower
// c[co][l] = b[co] + sum_{ci,k} w[co][ci][k] * h[ci][l + (k-1)*dil]  (zero pad)
// h_out = gelu(c) + c
// block: 64 co x 64 l, one chunk; grid (8 ltiles, 4 cotiles, 256 chunks)
__global__ __launch_bounds__(256) void k_conv(
    const bf16* __restrict__ hin, bf16* __restrict__ hout,
    const float* __restrict__ wl,   // transposed layer weights [(ci*3+k)*256+co]
    const float* __restrict__ b, int dil){
  __shared__ float Ws[16 * 3 * 64];   // [ci][k][co]
  __shared__ float Xs[16 * 3 * 64];   // [ci][k][j]
  const int n   = blockIdx.z;
  const int co0 = blockIdx.y * 64;
  const int l0  = blockIdx.x * 64;
  const int tid = threadIdx.x;
  const int lg  = tid & 15;   // -> 4 l
  const int cg  = tid >> 4;   // -> 4 co

  float acc[4][4];
  #pragma unroll
  for (int i = 0; i < 4; ++i){
    const float bv = b[co0 + cg * 4 + i];
    acc[i][0] = bv; acc[i][1] = bv; acc[i][2] = bv; acc[i][3] = bv;
  }

  const bf16* hrow = hin + (size_t)n * HIDDEN * CHUNK;

  for (int ci0 = 0; ci0 < HIDDEN; ci0 += 16){
    __syncthreads();
    // stage W: 16ci x 3k x 64co (coalesced from transposed layout)
    for (int i = tid; i < 16 * 3 * 64; i += 256){
      const int co   = i & 63;
      const int rest = i >> 6;                // (ci*3+k) within tile
      Ws[i] = wl[(size_t)(ci0 * 3 + rest) * HIDDEN + co0 + co];
    }
    // stage X: 16ci x 3k x 64j with zero pad
    for (int i = tid; i < 16 * 3 * 64; i += 256){
      const int j    = i & 63;
      const int rest = i >> 6;
      const int k    = rest % 3;
      const int ci   = rest / 3;
      const int l    = l0 + j + (k - 1) * dil;
      float v = 0.0f;
      if (l >= 0 && l < CHUNK) v = b2f(hrow[(ci0 + ci) * CHUNK + l]);
      Xs[i] = v;
    }
    __syncthreads();

    #pragma unroll 4
    for (int ci = 0; ci < 16; ++ci){
      #pragma unroll
      for (int k = 0; k < 3; ++k){
        const float4 wv = *(const float4*)(Ws + ((ci * 3 + k) << 6) + (cg << 2));
        const float4 xv = *(const float4*)(Xs + ((ci * 3 + k) << 6) + (lg << 2));
        acc[0][0] += wv.x * xv.x; acc[0][1] += wv.x * xv.y; acc[0][2] += wv.x * xv.z; acc[0][3] += wv.x * xv.w;
        acc[1][0] += wv.y * xv.x; acc[1][1] += wv.y * xv.y; acc[1][2] += wv.y * xv.z; acc[1][3] += wv.y * xv.w;
        acc[2][0] += wv.z * xv.x; acc[2][1] += wv.z * xv.y; acc[2][2] += wv.z * xv.z; acc[2][3] += wv.z * xv.w;
        acc[3][0] += wv.w * xv.x; acc[3][1] += wv.w * xv.y; acc[3][2] += wv.w * xv.z; acc[3][3] += wv.w * xv.w;
      }
    }
  }

  const float is2 = 0.70710678118654752f;
  #pragma unroll
  for (int i = 0; i < 4; ++i){
    bf16 ov[4];
    #pragma unroll
    for (int j = 0; j < 4; ++j){
      const float c = acc[i][j];
      const float g = 0.5f * c * (1.0f + erff(c * is2));   // exact gelu
      ov[j] = f2b(g + c);
    }
    *(uint2*)(hout + (size_t)(n * HIDDEN + co0 + cg * 4 + i) * CHUNK + l0 + lg * 4)
        = *(uint2*)ov;
  }
}

// ---------------------------------------------------------------- heads
// profile[n][l] = b_prof + sum_{ci,k} w_prof[ci][k] * h[ci][l + k - 9]
// atpm[n] = mask * (mean_l sum_ci ... ) ; out = [atpm(256) | profile(131072)]
__global__ __launch_bounds__(256) void k_head(
    const bf16* __restrict__ h, const float* __restrict__ wprof,
    const float* __restrict__ bprof, const float* __restrict__ watpm,
    const float* __restrict__ batpm, const int* __restrict__ n_peaks,
    float* __restrict__ out){
  __shared__ float hs[CHUNK];
  __shared__ float wp[KPROF];
  __shared__ float red[4];
  const int n   = blockIdx.x;
  const int tid = threadIdx.x;
  const bf16* hrow = h + (size_t)n * HIDDEN * CHUNK;

  float acc0 = 0.0f, acc1 = 0.0f, psum = 0.0f;
  for (int ci = 0; ci < HIDDEN; ++ci){
    __syncthreads();
    hs[tid]       = b2f(hrow[ci * CHUNK + tid]);
    hs[tid + 256] = b2f(hrow[ci * CHUNK + tid + 256]);
    if (tid < KPROF) wp[tid] = wprof[ci * KPROF + tid];
    __syncthreads();
    psum += watpm[ci] * (hs[tid] + hs[tid + 256]);
    #pragma unroll
    for (int k = 0; k < KPROF; ++k){
      const int i0 = tid + k - 9;
      const int i1 = tid + 256 + k - 9;
      if (i0 >= 0)    acc0 += wp[k] * hs[i0];       // i0 < 512 always (max 266)
      if (i1 < CHUNK) acc1 += wp[k] * hs[i1];       // i1 >= 0 always
    }
  }
  out[256 + n * CHUNK + tid]       = acc0 + bprof[0];
  out[256 + n * CHUNK + tid + 256] = acc1 + bprof[0];

  float p = psum;
  #pragma unroll
  for (int off = 32; off > 0; off >>= 1) p += __shfl_down(p, off, 64);
  if ((tid & 63) == 0) red[tid >> 6] = p;
  __syncthreads();
  if (tid == 0){
    const float total = red[0] + red[1] + red[2] + red[3];
    const float atpm  = total * (1.0f / 512.0f) + batpm[0];
    const int bb = n >> 7, pk = n & 127;
    out[n] = (pk < n_peaks[bb]) ? atpm : 0.0f;
  }
}

// ---------------------------------------------------------------- launcher
extern "C" void kernel_launch(void* const* d_in, const int* in_sizes, int n_in,
                              void* d_out, int out_size, void* d_ws, size_t ws_size,
                              hipStream_t stream){
  const float* x       = (const float*)d_in[0];
  const float* w_proj  = (const float*)d_in[1];
  const float* tower_w = (const float*)d_in[2];
  const float* tower_b = (const float*)d_in[3];
  const float* w_prof  = (const float*)d_in[4];
  const float* b_prof  = (const float*)d_in[5];
  const float* w_atpm  = (const float*)d_in[6];
  const float* b_atpm  = (const float*)d_in[7];
  const int*   n_peaks = (const int*)d_in[8];
  float* out = (float*)d_out;

  const size_t HBYTES = (size_t)NCHUNK * HIDDEN * CHUNK * sizeof(bf16); // 67108864
  char* ws = (char*)d_ws;
  bf16*  h0   = (bf16*)(ws);
  bf16*  h1   = (bf16*)(ws + HBYTES);
  float* wt   = (float*)(ws + 2 * HBYTES);                       // 283*256 f32
  float* wtow = (float*)(ws + 2 * HBYTES + 290816);              // 7*196608 f32

  k_transpose_wproj<<<(MOTIF * HIDDEN + 255) / 256, 256, 0, stream>>>(w_proj, wt);
  k_transpose_tower<<<(DEPTH * HIDDEN * HIDDEN * 3 + 255) / 256, 256, 0, stream>>>(tower_w, wtow);

  dim3 gproj(NTOK / 32, 2);
  k_proj<<<gproj, 256, 0, stream>>>(x, wt, h0);

  bf16* cur = h0; bf16* nxt = h1;
  for (int i = 0; i < DEPTH; ++i){
    const int dil = 2 << i;               // 2^(i+1)
    dim3 g(CHUNK / 64, HIDDEN / 64, NCHUNK);
    k_conv<<<g, 256, 0, stream>>>(cur, nxt,
                                  wtow + (size_t)i * HIDDEN * HIDDEN * 3,
                                  tower_b + i * HIDDEN, dil);
    bf16* t = cur; cur = nxt; nxt = t;
  }

  k_head<<<NCHUNK, 256, 0, stream>>>(cur, w_prof, b_prof, w_atpm, b_atpm,
                                     n_peaks, out);
}

// Round 2
// 1317.380 us; speedup vs baseline: 5.4198x; 5.4198x over previous
//
#include <hip/hip_runtime.h>
#include <hip/hip_bf16.h>
#include <math.h>

#define MOTIF  283
#define HIDDEN 256
#define DEPTH  7
#define KPROF  20
#define CHUNK  512
#define NCHUNK 256
#define NTOK   131072
#define BK     32

using bf16 = __hip_bfloat16;
typedef short bf16x8 __attribute__((ext_vector_type(8)));
typedef float f32x4  __attribute__((ext_vector_type(4)));

__device__ __forceinline__ float gelu_res(float c){
  // exact gelu(c) + c
  return 0.5f * c * (1.0f + erff(c * 0.70710678118654752f)) + c;
}

// ------------------------------------------------------------- prep kernels
// wtowT[layer][tap][co][ci] (bf16) from tower_w[layer][co][ci][tap] (f32)
__global__ __launch_bounds__(256) void k_prep_tower(
    const float* __restrict__ w, bf16* __restrict__ wt){
  const int idx = blockIdx.x * 256 + threadIdx.x;
  if (idx < DEPTH * 3 * HIDDEN * HIDDEN){
    const int ci   = idx & 255;
    const int co   = (idx >> 8) & 255;
    const int rest = idx >> 16;            // layer*3 + tap
    const int layer = rest / 3, tap = rest % 3;
    wt[idx] = __float2bfloat16(
        w[(((size_t)layer * HIDDEN + co) * HIDDEN + ci) * 3 + tap]);
  }
}

// wheadT[k][ci] bf16: rows 0..19 = wprof[ci][k], row 20 = watpm[ci], 21..31 = 0
__global__ __launch_bounds__(256) void k_prep_whead(
    const float* __restrict__ wprof, const float* __restrict__ watpm,
    bf16* __restrict__ wh){
  const int idx = blockIdx.x * 256 + threadIdx.x;   // k*256 + ci
  if (idx < 32 * 256){
    const int k = idx >> 8, ci = idx & 255;
    float v = 0.0f;
    if (k < KPROF) v = wprof[ci * KPROF + k];
    else if (k == KPROF) v = watpm[ci];
    wh[idx] = __float2bfloat16(v);
  }
}

// ------------------------------------------------------------- projection
// h0[token][co] = sum_m x[token][m] * wproj[co][m]   (MFMA, K padded 283->288)
// block: 128 co x 128 tok; 4 waves 2x2, each 64x64
__global__ __launch_bounds__(256, 2) void k_proj(
    const float* __restrict__ x, const float* __restrict__ wproj,
    bf16* __restrict__ h0){
  __shared__ __align__(16) bf16 Ws[128 * BK];   // [co][m]
  __shared__ __align__(16) bf16 Xs[128 * BK];   // [tok][m]
  const int t0  = blockIdx.x * 128;
  const int co0 = blockIdx.y * 128;
  const int tid = threadIdx.x;
  const int wid = tid >> 6, lane = tid & 63;
  const int lr = lane & 15, kq = lane >> 4;
  const int mw = wid & 1, nw = wid >> 1;

  f32x4 acc[4][4];
  #pragma unroll
  for (int mt = 0; mt < 4; ++mt)
    #pragma unroll
    for (int nt = 0; nt < 4; ++nt) acc[mt][nt] = (f32x4){0.f, 0.f, 0.f, 0.f};

  for (int m0 = 0; m0 < 288; m0 += BK){
    __syncthreads();
    for (int i = tid; i < 1024; i += 256){
      const int row = i >> 3, q = i & 7;
      bf16 t4[4];
      #pragma unroll
      for (int e = 0; e < 4; ++e){
        const int m = m0 + q * 4 + e;
        t4[e] = __float2bfloat16(
            m < MOTIF ? wproj[(size_t)(co0 + row) * MOTIF + m] : 0.0f);
      }
      *(uint2*)(Ws + row * BK + q * 4) = *(uint2*)t4;
    }
    for (int i = tid; i < 1024; i += 256){
      const int row = i >> 3, q = i & 7;
      bf16 t4[4];
      #pragma unroll
      for (int e = 0; e < 4; ++e){
        const int m = m0 + q * 4 + e;
        t4[e] = __float2bfloat16(
            m < MOTIF ? x[(size_t)(t0 + row) * MOTIF + m] : 0.0f);
      }
      *(uint2*)(Xs + row * BK + q * 4) = *(uint2*)t4;
    }
    __syncthreads();
    bf16x8 a[4], b[4];
    #pragma unroll
    for (int mt = 0; mt < 4; ++mt)
      a[mt] = *(const bf16x8*)(Ws + (mw * 64 + mt * 16 + lr) * BK + kq * 8);
    #pragma unroll
    for (int nt = 0; nt < 4; ++nt)
      b[nt] = *(const bf16x8*)(Xs + (nw * 64 + nt * 16 + lr) * BK + kq * 8);
    #pragma unroll
    for (int mt = 0; mt < 4; ++mt)
      #pragma unroll
      for (int nt = 0; nt < 4; ++nt)
        acc[mt][nt] = __builtin_amdgcn_mfma_f32_16x16x32_bf16(
            a[mt], b[nt], acc[mt][nt], 0, 0, 0);
  }

  #pragma unroll
  for (int mt = 0; mt < 4; ++mt){
    const int co = co0 + mw * 64 + mt * 16 + kq * 4;
    #pragma unroll
    for (int nt = 0; nt < 4; ++nt){
      const int tok = t0 + nw * 64 + nt * 16 + lr;
      bf16 ov[4];
      #pragma unroll
      for (int r = 0; r < 4; ++r) ov[r] = __float2bfloat16(acc[mt][nt][r]);
      *(uint2*)(h0 + (size_t)tok * HIDDEN + co) = *(uint2*)ov;
    }
  }
}

// ------------------------------------------------------------- conv tower
// hout[l][co] = gelu(c)+c, c = bias[co] + sum_{tap,ci} W[tap][co][ci]*h[l+(tap-1)d][ci]
// block: one chunk, 256 co x 64 l; A-fragments direct from global (L2-hot W)
__global__ __launch_bounds__(256, 3) void k_conv(
    const bf16* __restrict__ hin, bf16* __restrict__ hout,
    const bf16* __restrict__ wl,     // [3][256 co][256 ci]
    const float* __restrict__ bias, int dil){
  __shared__ __align__(16) bf16 Xs[3 * 64 * BK];   // [tap][l][ci] 12 KB
  const int n  = blockIdx.y;
  const int l0 = blockIdx.x * 64;
  const int tid = threadIdx.x;
  const int wid = tid >> 6, lane = tid & 63;
  const int lr = lane & 15, kq = lane >> 4;
  const int cow = wid * 64;

  f32x4 acc[4][4];
  #pragma unroll
  for (int mt = 0; mt < 4; ++mt)
    #pragma unroll
    for (int nt = 0; nt < 4; ++nt) acc[mt][nt] = (f32x4){0.f, 0.f, 0.f, 0.f};

  const bf16* hbase = hin + (size_t)n * CHUNK * HIDDEN;

  for (int ci0 = 0; ci0 < HIDDEN; ci0 += BK){
    __syncthreads();
    for (int i = tid; i < 768; i += 256){
      const int row = i >> 2, q = i & 3;       // row = tap*64 + j
      const int tap = row >> 6, j = row & 63;
      const int l = l0 + j + (tap - 1) * dil;
      uint4 v = {0u, 0u, 0u, 0u};
      if (l >= 0 && l < CHUNK)
        v = *(const uint4*)(hbase + (size_t)l * HIDDEN + ci0 + q * 8);
      *(uint4*)(Xs + row * BK + q * 8) = v;
    }
    __syncthreads();
    #pragma unroll
    for (int tap = 0; tap < 3; ++tap){
      bf16x8 a[4], b[4];
      #pragma unroll
      for (int mt = 0; mt < 4; ++mt)
        a[mt] = *(const bf16x8*)(
            wl + (size_t)(tap * 256 + cow + mt * 16 + lr) * HIDDEN + ci0 + kq * 8);
      #pragma unroll
      for (int nt = 0; nt < 4; ++nt)
        b[nt] = *(const bf16x8*)(Xs + (tap * 64 + nt * 16 + lr) * BK + kq * 8);
      #pragma unroll
      for (int mt = 0; mt < 4; ++mt)
        #pragma unroll
        for (int nt = 0; nt < 4; ++nt)
          acc[mt][nt] = __builtin_amdgcn_mfma_f32_16x16x32_bf16(
              a[mt], b[nt], acc[mt][nt], 0, 0, 0);
    }
  }

  bf16* obase = hout + (size_t)n * CHUNK * HIDDEN;
  #pragma unroll
  for (int mt = 0; mt < 4; ++mt){
    const int co = cow + mt * 16 + kq * 4;
    const float b0 = bias[co], b1 = bias[co + 1];
    const float b2 = bias[co + 2], b3 = bias[co + 3];
    #pragma unroll
    for (int nt = 0; nt < 4; ++nt){
      const int l = l0 + nt * 16 + lr;
      bf16 ov[4];
      ov[0] = __float2bfloat16(gelu_res(acc[mt][nt][0] + b0));
      ov[1] = __float2bfloat16(gelu_res(acc[mt][nt][1] + b1));
      ov[2] = __float2bfloat16(gelu_res(acc[mt][nt][2] + b2));
      ov[3] = __float2bfloat16(gelu_res(acc[mt][nt][3] + b3));
      *(uint2*)(obase + (size_t)l * HIDDEN + co) = *(uint2*)ov;
    }
  }
}

// ------------------------------------------------------------- head GEMM
// PT[k][token] = sum_ci h[token][ci] * wheadT[k][ci]   (k 0..31, 21 useful)
__global__ __launch_bounds__(256, 2) void k_head(
    const bf16* __restrict__ h, const bf16* __restrict__ wheadT,
    float* __restrict__ PT){
  __shared__ __align__(16) bf16 Xs[128 * BK];     // [tok][ci] 8 KB
  __shared__ __align__(16) bf16 Wh[32 * 256];     // 16 KB, whole head weight
  const int t0 = blockIdx.x * 128;
  const int tid = threadIdx.x;
  const int wid = tid >> 6, lane = tid & 63;
  const int lr = lane & 15, kq = lane >> 4;
  const int mw = wid & 1, nw = wid >> 1;

  for (int i = tid; i < 1024; i += 256)
    ((uint4*)Wh)[i] = ((const uint4*)wheadT)[i];

  f32x4 acc[4];
  #pragma unroll
  for (int mt = 0; mt < 4; ++mt) acc[mt] = (f32x4){0.f, 0.f, 0.f, 0.f};

  for (int ci0 = 0; ci0 < HIDDEN; ci0 += BK){
    __syncthreads();
    for (int i = tid; i < 512; i += 256){
      const int row = i >> 2, q = i & 3;
      *(uint4*)(Xs + row * BK + q * 8) =
          *(const uint4*)(h + (size_t)(t0 + row) * HIDDEN + ci0 + q * 8);
    }
    __syncthreads();
    const bf16x8 b = *(const bf16x8*)(Wh + (nw * 16 + lr) * 256 + ci0 + kq * 8);
    #pragma unroll
    for (int mt = 0; mt < 4; ++mt){
      const bf16x8 a = *(const bf16x8*)(Xs + (mw * 64 + mt * 16 + lr) * BK + kq * 8);
      acc[mt] = __builtin_amdgcn_mfma_f32_16x16x32_bf16(a, b, acc[mt], 0, 0, 0);
    }
  }
  const int k_out = nw * 16 + lr;
  #pragma unroll
  for (int mt = 0; mt < 4; ++mt){
    const int tok = t0 + mw * 64 + mt * 16 + kq * 4;
    *(f32x4*)(PT + (size_t)k_out * NTOK + tok) = acc[mt];
  }
}

// ------------------------------------------------------------- tap combine
__global__ __launch_bounds__(256) void k_combine(
    const float* __restrict__ PT, const float* __restrict__ bprof,
    float* __restrict__ out){
  const int t = blockIdx.x * 256 + threadIdx.x;
  const int n = t >> 9, l = t & 511;
  float acc = bprof[0];
  const float* base = PT + ((size_t)n << 9);
  #pragma unroll
  for (int k = 0; k < KPROF; ++k){
    const int j = l + k - 9;
    if ((unsigned)j < CHUNK) acc += base[(size_t)k * NTOK + j];
  }
  out[NCHUNK + t] = acc;
}

// ------------------------------------------------------------- atpm pool
__global__ __launch_bounds__(256) void k_atpm(
    const float* __restrict__ PT, const float* __restrict__ batpm,
    const int* __restrict__ n_peaks, float* __restrict__ out){
  __shared__ float red[4];
  const int n = blockIdx.x, tid = threadIdx.x;
  const float* row = PT + (size_t)KPROF * NTOK + ((size_t)n << 9);
  float p = row[tid] + row[tid + 256];
  #pragma unroll
  for (int off = 32; off > 0; off >>= 1) p += __shfl_down(p, off, 64);
  if ((tid & 63) == 0) red[tid >> 6] = p;
  __syncthreads();
  if (tid == 0){
    const float s = red[0] + red[1] + red[2] + red[3];
    const float a = s * (1.0f / 512.0f) + batpm[0];
    out[n] = ((n & 127) < n_peaks[n >> 7]) ? a : 0.0f;
  }
}

// ------------------------------------------------------------- launcher
extern "C" void kernel_launch(void* const* d_in, const int* in_sizes, int n_in,
                              void* d_out, int out_size, void* d_ws, size_t ws_size,
                              hipStream_t stream){
  const float* x       = (const float*)d_in[0];
  const float* w_proj  = (const float*)d_in[1];
  const float* tower_w = (const float*)d_in[2];
  const float* tower_b = (const float*)d_in[3];
  const float* w_prof  = (const float*)d_in[4];
  const float* b_prof  = (const float*)d_in[5];
  const float* w_atpm  = (const float*)d_in[6];
  const float* b_atpm  = (const float*)d_in[7];
  const int*   n_peaks = (const int*)d_in[8];
  float* out = (float*)d_out;

  char* ws = (char*)d_ws;
  bf16*  h0     = (bf16*)ws;                        // 67108864 B
  bf16*  h1     = (bf16*)(ws + 67108864);           // 67108864 B
  float* PT     = (float*)(ws + 134217728);         // 32*131072*4 = 16777216 B
  bf16*  wtowT  = (bf16*)(ws + 150994944);          // 2752512 B
  bf16*  wheadT = (bf16*)(ws + 153747456);          // 16384 B

  k_prep_tower<<<5376, 256, 0, stream>>>(tower_w, wtowT);
  k_prep_whead<<<32, 256, 0, stream>>>(w_prof, w_atpm, wheadT);

  k_proj<<<dim3(1024, 2), 256, 0, stream>>>(x, w_proj, h0);

  bf16* cur = h0; bf16* nxt = h1;
  for (int i = 0; i < DEPTH; ++i){
    k_conv<<<dim3(8, 256), 256, 0, stream>>>(
        cur, nxt, wtowT + (size_t)i * 3 * HIDDEN * HIDDEN,
        tower_b + i * HIDDEN, 2 << i);
    bf16* t = cur; cur = nxt; nxt = t;
  }

  k_head<<<1024, 256, 0, stream>>>(cur, wheadT, PT);
  k_combine<<<512, 256, 0, stream>>>(PT, b_prof, out);
  k_atpm<<<256, 256, 0, stream>>>(PT, b_atpm, n_peaks, out);
}

// Round 3
// 1084.716 us; speedup vs baseline: 6.5823x; 1.2145x over previous
//
#include <hip/hip_runtime.h>
#include <hip/hip_bf16.h>
#include <math.h>

#define MOTIF  283
#define KPAD   288
#define HIDDEN 256
#define DEPTH  7
#define KPROF  20
#define CHUNK  512
#define NCHUNK 256
#define NTOK   131072
#define BK     32
#define LTILE  128

using bf16 = __hip_bfloat16;
typedef short bf16x8 __attribute__((ext_vector_type(8)));
typedef float f32x4  __attribute__((ext_vector_type(4)));

__device__ __forceinline__ float gelu_res(float c){
  return 0.5f * c * (1.0f + erff(c * 0.70710678118654752f)) + c;   // gelu(c)+c
}

// ------------------------------------------------------------- prep kernels
// wtowT[layer][tap][co][ci] (bf16) from tower_w[layer][co][ci][tap] (f32)
__global__ __launch_bounds__(256) void k_prep_tower(
    const float* __restrict__ w, bf16* __restrict__ wt){
  const int idx = blockIdx.x * 256 + threadIdx.x;
  if (idx < DEPTH * 3 * HIDDEN * HIDDEN){
    const int ci   = idx & 255;
    const int co   = (idx >> 8) & 255;
    const int rest = idx >> 16;            // layer*3 + tap
    const int layer = rest / 3, tap = rest % 3;
    wt[idx] = __float2bfloat16(
        w[(((size_t)layer * HIDDEN + co) * HIDDEN + ci) * 3 + tap]);
  }
}

// wprojT[co][KPAD] bf16, zero-padded m>=283
__global__ __launch_bounds__(256) void k_prep_wproj(
    const float* __restrict__ w, bf16* __restrict__ wt){
  const int idx = blockIdx.x * 256 + threadIdx.x;
  if (idx < HIDDEN * KPAD){
    const int co = idx / KPAD, m = idx % KPAD;
    wt[idx] = __float2bfloat16(m < MOTIF ? w[(size_t)co * MOTIF + m] : 0.0f);
  }
}

// wheadT[k][ci] bf16: rows 0..19 = wprof[ci][k], row 20 = watpm[ci], 21..31 = 0
__global__ __launch_bounds__(256) void k_prep_whead(
    const float* __restrict__ wprof, const float* __restrict__ watpm,
    bf16* __restrict__ wh){
  const int idx = blockIdx.x * 256 + threadIdx.x;
  if (idx < 32 * 256){
    const int k = idx >> 8, ci = idx & 255;
    float v = 0.0f;
    if (k < KPROF) v = wprof[ci * KPROF + k];
    else if (k == KPROF) v = watpm[ci];
    wh[idx] = __float2bfloat16(v);
  }
}

// ------------------------------------------------------------- projection
// h0[token][co] = sum_m x[token][m] * wproj[co][m]
// block: ALL 256 co x 64 tok; stage full-K X tile once, then barrier-free K-loop
__global__ __launch_bounds__(256, 3) void k_proj(
    const float* __restrict__ x, const bf16* __restrict__ wprojT,
    bf16* __restrict__ h0){
  __shared__ __align__(16) bf16 Xs[64 * KPAD];   // 36 KB
  const int t0  = blockIdx.x * 64;
  const int tid = threadIdx.x;
  const int wid = tid >> 6, lane = tid & 63;
  const int lr = lane & 15, kq = lane >> 4;
  const int cow = wid * 64;

  // stage + convert: lanes along m (coalesced 4B), rows = tokens
  for (int r = wid; r < 64; r += 4){
    const float* xrow = x + (size_t)(t0 + r) * MOTIF;
    #pragma unroll
    for (int mi = 0; mi < 5; ++mi){
      const int m = lane + mi * 64;
      if (m < KPAD)
        Xs[r * KPAD + m] = __float2bfloat16(m < MOTIF ? xrow[m] : 0.0f);
    }
  }
  __syncthreads();

  f32x4 acc[4][4];
  #pragma unroll
  for (int mt = 0; mt < 4; ++mt)
    #pragma unroll
    for (int nt = 0; nt < 4; ++nt) acc[mt][nt] = (f32x4){0.f, 0.f, 0.f, 0.f};

  for (int m0 = 0; m0 < KPAD; m0 += BK){
    bf16x8 a[4], b[4];
    #pragma unroll
    for (int mt = 0; mt < 4; ++mt)
      a[mt] = *(const bf16x8*)(
          wprojT + (size_t)(cow + mt * 16 + lr) * KPAD + m0 + kq * 8);
    #pragma unroll
    for (int nt = 0; nt < 4; ++nt)
      b[nt] = *(const bf16x8*)(Xs + (nt * 16 + lr) * KPAD + m0 + kq * 8);
    #pragma unroll
    for (int mt = 0; mt < 4; ++mt)
      #pragma unroll
      for (int nt = 0; nt < 4; ++nt)
        acc[mt][nt] = __builtin_amdgcn_mfma_f32_16x16x32_bf16(
            a[mt], b[nt], acc[mt][nt], 0, 0, 0);
  }

  #pragma unroll
  for (int mt = 0; mt < 4; ++mt){
    const int co = cow + mt * 16 + kq * 4;
    #pragma unroll
    for (int nt = 0; nt < 4; ++nt){
      const int tok = t0 + nt * 16 + lr;
      bf16 ov[4];
      #pragma unroll
      for (int r = 0; r < 4; ++r) ov[r] = __float2bfloat16(acc[mt][nt][r]);
      *(uint2*)(h0 + (size_t)tok * HIDDEN + co) = *(uint2*)ov;
    }
  }
}

// ------------------------------------------------------------- conv tower
// hout[l][co] = gelu(c)+c, c = bias[co] + sum_{tap,ci} W[tap][co][ci]*h[l+(tap-1)d][ci]
// block: one chunk, 256 co x 128 l; A direct from global (L2-hot W)
__global__ __launch_bounds__(256, 2) void k_conv(
    const bf16* __restrict__ hin, bf16* __restrict__ hout,
    const bf16* __restrict__ wl,     // [3][256 co][256 ci]
    const float* __restrict__ bias, int dil){
  __shared__ __align__(16) bf16 Xs[3 * LTILE * BK];   // 24 KB
  const int n  = blockIdx.y;
  const int l0 = blockIdx.x * LTILE;
  const int tid = threadIdx.x;
  const int wid = tid >> 6, lane = tid & 63;
  const int lr = lane & 15, kq = lane >> 4;
  const int cow = wid * 64;

  f32x4 acc[4][8];
  #pragma unroll
  for (int mt = 0; mt < 4; ++mt)
    #pragma unroll
    for (int nt = 0; nt < 8; ++nt) acc[mt][nt] = (f32x4){0.f, 0.f, 0.f, 0.f};

  const bf16* hbase = hin + (size_t)n * CHUNK * HIDDEN;

  for (int ci0 = 0; ci0 < HIDDEN; ci0 += BK){
    __syncthreads();
    for (int i = tid; i < 3 * LTILE * 4; i += 256){
      const int row = i >> 2, q = i & 3;       // row = tap*128 + j
      const int tap = row >> 7, j = row & 127;
      const int l = l0 + j + (tap - 1) * dil;
      uint4 v = {0u, 0u, 0u, 0u};
      if ((unsigned)l < CHUNK)
        v = *(const uint4*)(hbase + (size_t)l * HIDDEN + ci0 + q * 8);
      *(uint4*)(Xs + row * BK + q * 8) = v;
    }
    __syncthreads();
    #pragma unroll
    for (int tap = 0; tap < 3; ++tap){
      bf16x8 a[4], b[8];
      #pragma unroll
      for (int mt = 0; mt < 4; ++mt)
        a[mt] = *(const bf16x8*)(
            wl + (size_t)(tap * 256 + cow + mt * 16 + lr) * HIDDEN + ci0 + kq * 8);
      #pragma unroll
      for (int nt = 0; nt < 8; ++nt)
        b[nt] = *(const bf16x8*)(Xs + (tap * LTILE + nt * 16 + lr) * BK + kq * 8);
      #pragma unroll
      for (int mt = 0; mt < 4; ++mt)
        #pragma unroll
        for (int nt = 0; nt < 8; ++nt)
          acc[mt][nt] = __builtin_amdgcn_mfma_f32_16x16x32_bf16(
              a[mt], b[nt], acc[mt][nt], 0, 0, 0);
    }
  }

  bf16* obase = hout + (size_t)n * CHUNK * HIDDEN;
  #pragma unroll
  for (int mt = 0; mt < 4; ++mt){
    const int co = cow + mt * 16 + kq * 4;
    const float b0 = bias[co], b1 = bias[co + 1];
    const float b2 = bias[co + 2], b3 = bias[co + 3];
    #pragma unroll
    for (int nt = 0; nt < 8; ++nt){
      const int l = l0 + nt * 16 + lr;
      bf16 ov[4];
      ov[0] = __float2bfloat16(gelu_res(acc[mt][nt][0] + b0));
      ov[1] = __float2bfloat16(gelu_res(acc[mt][nt][1] + b1));
      ov[2] = __float2bfloat16(gelu_res(acc[mt][nt][2] + b2));
      ov[3] = __float2bfloat16(gelu_res(acc[mt][nt][3] + b3));
      *(uint2*)(obase + (size_t)l * HIDDEN + co) = *(uint2*)ov;
    }
  }
}

// ------------------------------------------------------------- head GEMM
// PT[k][token] = sum_ci h[token][ci] * wheadT[k][ci]   (k 0..31, 21 useful)
__global__ __launch_bounds__(256, 2) void k_head(
    const bf16* __restrict__ h, const bf16* __restrict__ wheadT,
    float* __restrict__ PT){
  __shared__ __align__(16) bf16 Xs[128 * BK];     // 8 KB
  __shared__ __align__(16) bf16 Wh[32 * 256];     // 16 KB
  const int t0 = blockIdx.x * 128;
  const int tid = threadIdx.x;
  const int wid = tid >> 6, lane = tid & 63;
  const int lr = lane & 15, kq = lane >> 4;
  const int mw = wid & 1, nw = wid >> 1;

  for (int i = tid; i < 1024; i += 256)
    ((uint4*)Wh)[i] = ((const uint4*)wheadT)[i];

  f32x4 acc[4];
  #pragma unroll
  for (int mt = 0; mt < 4; ++mt) acc[mt] = (f32x4){0.f, 0.f, 0.f, 0.f};

  for (int ci0 = 0; ci0 < HIDDEN; ci0 += BK){
    __syncthreads();
    for (int i = tid; i < 512; i += 256){
      const int row = i >> 2, q = i & 3;
      *(uint4*)(Xs + row * BK + q * 8) =
          *(const uint4*)(h + (size_t)(t0 + row) * HIDDEN + ci0 + q * 8);
    }
    __syncthreads();
    const bf16x8 b = *(const bf16x8*)(Wh + (nw * 16 + lr) * 256 + ci0 + kq * 8);
    #pragma unroll
    for (int mt = 0; mt < 4; ++mt){
      const bf16x8 a = *(const bf16x8*)(Xs + (mw * 64 + mt * 16 + lr) * BK + kq * 8);
      acc[mt] = __builtin_amdgcn_mfma_f32_16x16x32_bf16(a, b, acc[mt], 0, 0, 0);
    }
  }
  const int k_out = nw * 16 + lr;
  #pragma unroll
  for (int mt = 0; mt < 4; ++mt){
    const int tok = t0 + mw * 64 + mt * 16 + kq * 4;
    *(f32x4*)(PT + (size_t)k_out * NTOK + tok) = acc[mt];
  }
}

// ------------------------------------------------------------- tap combine
__global__ __launch_bounds__(256) void k_combine(
    const float* __restrict__ PT, const float* __restrict__ bprof,
    float* __restrict__ out){
  const int t = blockIdx.x * 256 + threadIdx.x;
  const int n = t >> 9, l = t & 511;
  float acc = bprof[0];
  const float* base = PT + ((size_t)n << 9);
  #pragma unroll
  for (int k = 0; k < KPROF; ++k){
    const int j = l + k - 9;
    if ((unsigned)j < CHUNK) acc += base[(size_t)k * NTOK + j];
  }
  out[NCHUNK + t] = acc;
}

// ------------------------------------------------------------- atpm pool
__global__ __launch_bounds__(256) void k_atpm(
    const float* __restrict__ PT, const float* __restrict__ batpm,
    const int* __restrict__ n_peaks, float* __restrict__ out){
  __shared__ float red[4];
  const int n = blockIdx.x, tid = threadIdx.x;
  const float* row = PT + (size_t)KPROF * NTOK + ((size_t)n << 9);
  float p = row[tid] + row[tid + 256];
  #pragma unroll
  for (int off = 32; off > 0; off >>= 1) p += __shfl_down(p, off, 64);
  if ((tid & 63) == 0) red[tid >> 6] = p;
  __syncthreads();
  if (tid == 0){
    const float s = red[0] + red[1] + red[2] + red[3];
    const float a = s * (1.0f / 512.0f) + batpm[0];
    out[n] = ((n & 127) < n_peaks[n >> 7]) ? a : 0.0f;
  }
}

// ------------------------------------------------------------- launcher
extern "C" void kernel_launch(void* const* d_in, const int* in_sizes, int n_in,
                              void* d_out, int out_size, void* d_ws, size_t ws_size,
                              hipStream_t stream){
  const float* x       = (const float*)d_in[0];
  const float* w_proj  = (const float*)d_in[1];
  const float* tower_w = (const float*)d_in[2];
  const float* tower_b = (const float*)d_in[3];
  const float* w_prof  = (const float*)d_in[4];
  const float* b_prof  = (const float*)d_in[5];
  const float* w_atpm  = (const float*)d_in[6];
  const float* b_atpm  = (const float*)d_in[7];
  const int*   n_peaks = (const int*)d_in[8];
  float* out = (float*)d_out;

  char* ws = (char*)d_ws;
  bf16*  h0     = (bf16*)ws;                        // 67108864 B
  bf16*  h1     = (bf16*)(ws + 67108864);           // 67108864 B
  float* PT     = (float*)(ws + 134217728);         // 16777216 B
  bf16*  wtowT  = (bf16*)(ws + 150994944);          // 2752512 B
  bf16*  wheadT = (bf16*)(ws + 153747456);          // 16384 B
  bf16*  wprojT = (bf16*)(ws + 153763840);          // 147456 B

  k_prep_tower<<<5376, 256, 0, stream>>>(tower_w, wtowT);
  k_prep_wproj<<<(HIDDEN * KPAD + 255) / 256, 256, 0, stream>>>(w_proj, wprojT);
  k_prep_whead<<<32, 256, 0, stream>>>(w_prof, w_atpm, wheadT);

  k_proj<<<NTOK / 64, 256, 0, stream>>>(x, wprojT, h0);

  bf16* cur = h0; bf16* nxt = h1;
  for (int i = 0; i < DEPTH; ++i){
    k_conv<<<dim3(CHUNK / LTILE, NCHUNK), 256, 0, stream>>>(
        cur, nxt, wtowT + (size_t)i * 3 * HIDDEN * HIDDEN,
        tower_b + i * HIDDEN, 2 << i);
    bf16* t = cur; cur = nxt; nxt = t;
  }

  k_head<<<1024, 256, 0, stream>>>(cur, wheadT, PT);
  k_combine<<<512, 256, 0, stream>>>(PT, b_prof, out);
  k_atpm<<<256, 256, 0, stream>>>(PT, b_atpm, n_peaks, out);
}